// Round 11
// baseline (66.878 us; speedup 1.0000x reference)
//
#include <hip/hip_runtime.h>
#include <hip/hip_bf16.h>

#define BB 16
#define SS 512
#define HH 768
#define RR 8
#define DD 512
#define CC 27
#define WW 256
#define NBLK 256

typedef __attribute__((ext_vector_type(8))) short short8;
typedef __attribute__((ext_vector_type(4))) float f32x4;

union PKu { unsigned short us[8]; uint4 u4; short8 s8; };

__device__ __forceinline__ unsigned short f32_to_bf16_rne(float v) {
    unsigned int u = __float_as_uint(v);
    unsigned int r = u + 0x7fffu + ((u >> 16) & 1u);
    return (unsigned short)(r >> 16);
}
__device__ __forceinline__ float bf16_to_f32(unsigned short u) {
    return __uint_as_float(((unsigned int)u) << 16);
}
__device__ __forceinline__ void glds16(const void* g, void* l) {
    __builtin_amdgcn_global_load_lds(
        (const __attribute__((address_space(1))) unsigned int*)g,
        (__attribute__((address_space(3))) unsigned int*)l, 16, 0, 0);
}

// barrier v3: zero shared-line RMWs.
//  arrive:  block b -> RELEASE store to flags[b*32] (own 128B line)
//  gather:  block 0, 256 lanes poll all flags in parallel
//  release: block 0 stores gen to 64 spread lines; <=4 spinners per line
__device__ __forceinline__ void gbar(int* flags, int* genl, int phase) {
    __syncthreads();
    int bid = blockIdx.x, t = threadIdx.x;
    if (t == 0)
        __hip_atomic_store(flags + bid * 32, phase, __ATOMIC_RELEASE,
                           __HIP_MEMORY_SCOPE_AGENT);
    if (bid == 0) {
        if (t < NBLK) {
            while (__hip_atomic_load(flags + t * 32, __ATOMIC_RELAXED,
                                     __HIP_MEMORY_SCOPE_AGENT) < phase)
                __builtin_amdgcn_s_sleep(2);
        }
        __syncthreads();
        if (t < 64)
            __hip_atomic_store(genl + t * 32, phase, __ATOMIC_RELEASE,
                               __HIP_MEMORY_SCOPE_AGENT);
        if (t == 0)
            (void)__hip_atomic_load(genl, __ATOMIC_ACQUIRE,
                                    __HIP_MEMORY_SCOPE_AGENT);
    } else if (t == 0) {
        while (__hip_atomic_load(genl + (bid & 63) * 32, __ATOMIC_RELAXED,
                                 __HIP_MEMORY_SCOPE_AGENT) < phase)
            __builtin_amdgcn_s_sleep(16);
        (void)__hip_atomic_load(genl + (bid & 63) * 32, __ATOMIC_ACQUIRE,
                                __HIP_MEMORY_SCOPE_AGENT);
    }
    __syncthreads();
}

// ---------------------------------------------------------------------------
// ws layout (bytes):
//   first_hidden : bf16[BB*WW][HH]   @ 0          (6291456)
//   rel_hidden   : bf16[BB*RR][HH]   @ 6291456    (196608)
//   w1t          : bf16[DD][2*HH]    @ 6488064    (1572864)
//   w2t          : bf16[32][DD]      @ 8060928    (32768)
//   h_word       : bf16[BB*WW][DD]   @ 8093696    (4194304)  (+b1 folded)
//   h_rel        : bf16[BB*RR][DD]   @ 12288000   (131072)
//   flags        : int[256*32]       @ 12419072   (32768)
//   genl         : int[64*32]        @ 12451840   (8192)
// ---------------------------------------------------------------------------

__global__ __launch_bounds__(512) void k_all(
    const float* __restrict__ hidden, const int* __restrict__ word_ids,
    const int* __restrict__ relpos, const float4* __restrict__ wrel4,
    const float* __restrict__ b_rel, const float* __restrict__ w1,
    const float* __restrict__ b1, const float* __restrict__ w2,
    const float* __restrict__ b2, float* __restrict__ out0,
    float* __restrict__ out_role, unsigned short* __restrict__ first_hidden,
    unsigned short* __restrict__ rel_hidden, unsigned short* __restrict__ w1t,
    unsigned short* __restrict__ w2t, unsigned short* __restrict__ h_word,
    unsigned short* __restrict__ h_rel, int* __restrict__ flags,
    int* __restrict__ genl) {
    __shared__ __align__(16) unsigned char smem[65536];
    int bid = blockIdx.x, t = threadIdx.x;
    int wv = t >> 6, lane = t & 63;

    // ============================ PHASE A: front ==========================
    for (int j = bid; j < 1233; j += NBLK) {
        if (j < 1024) {
            int row = j * 8 + wv;
            const float4* hid4 = (const float4*)hidden + (size_t)row * (HH / 4);
            float4 v[3];
            float acc = 0.f;
#pragma unroll
            for (int c = 0; c < 3; ++c) {
                v[c] = hid4[c * 64 + lane];
                float4 w = wrel4[c * 64 + lane];
                acc += v[c].x * w.x + v[c].y * w.y + v[c].z * w.z + v[c].w * w.w;
            }
#pragma unroll
            for (int off = 32; off > 0; off >>= 1) acc += __shfl_xor(acc, off, 64);
            if (lane == 0) out0[row] = acc + b_rel[0];
            int wid = word_ids[row];
            int s = row & (SS - 1);
            int prev = (s == 0) ? -1 : word_ids[row - 1];
            if (wid != prev) {
                int b = row >> 9;
                unsigned short* dst = first_hidden + (size_t)(b * WW + wid) * HH;
#pragma unroll
                for (int c = 0; c < 3; ++c) {
                    union { unsigned short us[4]; uint2 u2; } pk;
                    pk.us[0] = f32_to_bf16_rne(v[c].x);
                    pk.us[1] = f32_to_bf16_rne(v[c].y);
                    pk.us[2] = f32_to_bf16_rne(v[c].z);
                    pk.us[3] = f32_to_bf16_rne(v[c].w);
                    *(uint2*)(dst + c * 256 + lane * 4) = pk.u2;
                }
            }
        } else if (j < 1216) {
            unsigned short (*tile)[72] = (unsigned short(*)[72])smem;
            int x = j - 1024;
            int kt = x >> 3, ntc = x & 7;
            int i = t >> 3, j8 = (t & 7) * 8;
            const float* src = w1 + (size_t)(kt * 64 + i) * DD + ntc * 64 + j8;
            float4 f0 = *(const float4*)(src);
            float4 f1 = *(const float4*)(src + 4);
            tile[i][j8 + 0] = f32_to_bf16_rne(f0.x);
            tile[i][j8 + 1] = f32_to_bf16_rne(f0.y);
            tile[i][j8 + 2] = f32_to_bf16_rne(f0.z);
            tile[i][j8 + 3] = f32_to_bf16_rne(f0.w);
            tile[i][j8 + 4] = f32_to_bf16_rne(f1.x);
            tile[i][j8 + 5] = f32_to_bf16_rne(f1.y);
            tile[i][j8 + 6] = f32_to_bf16_rne(f1.z);
            tile[i][j8 + 7] = f32_to_bf16_rne(f1.w);
            __syncthreads();
            int jj = t >> 3, cb = (t & 7) * 8;
            PKu ov;
#pragma unroll
            for (int v = 0; v < 8; ++v) ov.us[v] = tile[cb + v][jj];
            *(uint4*)(w1t + (size_t)(ntc * 64 + jj) * (2 * HH) + kt * 64 + cb) = ov.u4;
        } else if (j == 1216) {
            for (int idx = t; idx < 32 * DD; idx += 512) {
                int n = idx >> 9, k = idx & (DD - 1);
                float v = (n < CC) ? w2[(size_t)k * CC + n] : 0.f;
                w2t[n * DD + k] = f32_to_bf16_rne(v);
            }
        } else {
            int* pres = (int*)smem;
            int b = j - 1217;
            if (t < WW) pres[t] = 0;
            __syncthreads();
            pres[word_ids[b * SS + t]] = 1;
            __syncthreads();
            if (t < WW && !pres[t]) {
                uint4 z = {0u, 0u, 0u, 0u};
                unsigned short* dst = first_hidden + (size_t)(b * WW + t) * HH;
#pragma unroll 4
                for (int c = 0; c < 96; ++c) *(uint4*)(dst + c * 8) = z;
            }
            for (int idx = t; idx < RR * 96; idx += 512) {
                int rr = idx / 96, c = idx % 96;
                int pos = relpos[b * RR + rr];
                const float* srow = hidden + (size_t)(b * SS + pos) * HH + c * 8;
                PKu pk;
#pragma unroll
                for (int e = 0; e < 8; ++e) pk.us[e] = f32_to_bf16_rne(srow[e]);
                *(uint4*)(rel_hidden + (size_t)(b * RR + rr) * HH + c * 8) = pk.u4;
            }
        }
        __syncthreads();
    }

    gbar(flags, genl, 1);

    // ============================ PHASE B: gemm ===========================
    // 128x64 tile, BK=64, dbuf, 8 waves (4x2), per wave 32x32.
    // XCD-bijective: job j (j<256) runs on block j (XCD j&7); all 8 nt-slices
    // of one mt share an XCD's L2 copy of A. h_rel tail on blocks 248..255.
    {
        unsigned char* a_s = smem;            // 2 x 16 KB
        unsigned char* b_s = smem + 32768;    // 2 x 8 KB
        int wr = wv >> 1, wc = wv & 1;
        int q = lane >> 4, r = lane & 15;
#pragma unroll 1
        for (int pass = 0; pass < 2; ++pass) {
            int j;
            if (pass == 0) j = bid;
            else { if (bid < 248) break; j = 256 + (bid - 248); }
            int nt, mt;
            if (j < 256) {
                int xcd = j & 7, k = j >> 3;
                mt = xcd + 8 * (k & 3);
                nt = k >> 2;
            } else { mt = 32; nt = j - 256; }
            bool isw = (mt < 32);
            const unsigned short* A = isw ? first_hidden : rel_hidden;
            unsigned short* C = isw ? h_word : h_rel;
            int kbase = isw ? 0 : HH;
            int m0 = isw ? mt * 128 : 0;

            const unsigned char* aP[2];
            const unsigned char* bP;
            unsigned lofa[2], lofb;
#pragma unroll
            for (int g = 0; g < 2; ++g) {
                int ci = g * 512 + t;
                int row = ci >> 3, ch = ci & 7;
                int sc = ch ^ (row & 7);
                aP[g] = (const unsigned char*)A + (size_t)(m0 + row) * (HH * 2) + sc * 16;
                lofa[g] = ci * 16;
            }
            {
                int row = t >> 3, ch = t & 7;
                int sc = ch ^ (row & 7);
                bP = (const unsigned char*)w1t + (size_t)(nt * 64 + row) * (2 * HH * 2)
                     + (size_t)kbase * 2 + sc * 16;
                lofb = t * 16;
            }
            int arow[2], brow[2];
#pragma unroll
            for (int mi = 0; mi < 2; ++mi) arow[mi] = wr * 32 + mi * 16 + r;
#pragma unroll
            for (int ni = 0; ni < 2; ++ni) brow[ni] = wc * 32 + ni * 16 + r;

            f32x4 acc[2][2];
#pragma unroll
            for (int mi = 0; mi < 2; ++mi)
#pragma unroll
                for (int ni = 0; ni < 2; ++ni) acc[mi][ni] = (f32x4){0.f, 0.f, 0.f, 0.f};

#pragma unroll
            for (int g = 0; g < 2; ++g) glds16(aP[g], a_s + lofa[g]);
            glds16(bP, b_s + lofb);
            __syncthreads();

            for (int kt = 0; kt < 12; ++kt) {
                if (kt < 11) {
                    unsigned na = ((kt + 1) & 1) * 16384;
                    unsigned nb = ((kt + 1) & 1) * 8192;
#pragma unroll
                    for (int g = 0; g < 2; ++g)
                        glds16(aP[g] + (kt + 1) * 128, a_s + na + lofa[g]);
                    glds16(bP + (kt + 1) * 128, b_s + nb + lofb);
                }
                unsigned ba = (kt & 1) * 16384;
                unsigned bb = (kt & 1) * 8192;
#pragma unroll
                for (int ks = 0; ks < 2; ++ks) {
                    int c = ks * 4 + q;
                    short8 bfr[2];
#pragma unroll
                    for (int ni = 0; ni < 2; ++ni)
                        bfr[ni] = *(const short8*)(b_s + bb + brow[ni] * 128 +
                                    ((c ^ (brow[ni] & 7)) << 4));
#pragma unroll
                    for (int mi = 0; mi < 2; ++mi) {
                        short8 af = *(const short8*)(a_s + ba + arow[mi] * 128 +
                                    ((c ^ (arow[mi] & 7)) << 4));
                        acc[mi][0] = __builtin_amdgcn_mfma_f32_16x16x32_bf16(
                            af, bfr[0], acc[mi][0], 0, 0, 0);
                        acc[mi][1] = __builtin_amdgcn_mfma_f32_16x16x32_bf16(
                            af, bfr[1], acc[mi][1], 0, 0, 0);
                    }
                }
                __syncthreads();
            }
            float bias[2];
#pragma unroll
            for (int ni = 0; ni < 2; ++ni) {
                int n = nt * 64 + wc * 32 + ni * 16 + r;
                bias[ni] = isw ? b1[n] : 0.f;
            }
#pragma unroll
            for (int mi = 0; mi < 2; ++mi) {
                int m = m0 + wr * 32 + mi * 16 + q * 4;
#pragma unroll
                for (int ni = 0; ni < 2; ++ni) {
                    int n = nt * 64 + wc * 32 + ni * 16 + r;
#pragma unroll
                    for (int reg = 0; reg < 4; ++reg)
                        C[(size_t)(m + reg) * DD + n] =
                            f32_to_bf16_rne(acc[mi][ni][reg] + bias[ni]);
                }
            }
        }
    }

    gbar(flags, genl, 2);

    // ============================ PHASE C: role ===========================
    {
        unsigned char* hw_s = smem;                        // 16 KB bf16 swz
        float (*hr_s)[DD] = (float(*)[DD])(smem + 16384);  // 16 KB f32
        unsigned char* w2_s = smem + 32768;                // 32 KB bf16 swz
        int wt = bid & 15, b = bid >> 4;
#pragma unroll
        for (int i = 0; i < 2; ++i) {
            int row = wv * 2 + i;
            const unsigned short* src = h_word +
                (size_t)(b * WW + wt * 16 + row) * DD + ((lane ^ (row & 7)) * 8);
            glds16(src, hw_s + row * 1024 + lane * 16);
        }
#pragma unroll
        for (int i = 0; i < 4; ++i) {
            int row = wv * 4 + i;
            const unsigned short* src = w2t + row * DD + ((lane ^ (row & 7)) * 8);
            glds16(src, w2_s + row * 1024 + lane * 16);
        }
        {
            int rr = wv, c = lane;
            PKu hv;
            hv.u4 = *(const uint4*)(h_rel + (size_t)(b * RR + rr) * DD + c * 8);
            float4 o0, o1;
            o0.x = bf16_to_f32(hv.us[0]); o0.y = bf16_to_f32(hv.us[1]);
            o0.z = bf16_to_f32(hv.us[2]); o0.w = bf16_to_f32(hv.us[3]);
            o1.x = bf16_to_f32(hv.us[4]); o1.y = bf16_to_f32(hv.us[5]);
            o1.z = bf16_to_f32(hv.us[6]); o1.w = bf16_to_f32(hv.us[7]);
            *(float4*)&hr_s[rr][c * 8]     = o0;
            *(float4*)&hr_s[rr][c * 8 + 4] = o1;
        }
        __syncthreads();
        int q = lane >> 4, wl = lane & 15;
        int rr = wv;
        unsigned wlx = (wl & 7) << 4;
        f32x4 acc[2];
#pragma unroll
        for (int ni = 0; ni < 2; ++ni) acc[ni] = (f32x4){0.f, 0.f, 0.f, 0.f};

#pragma unroll 2
        for (int ks = 0; ks < DD / 32; ++ks) {
            int c = 4 * ks + q;
            short8 bfr[2];
#pragma unroll
            for (int ni = 0; ni < 2; ++ni) {
                int n = ni * 16 + wl;
                bfr[ni] = *(const short8*)(w2_s + n * 1024 + ((c ^ (n & 7)) << 4));
            }
            PKu hw;
            hw.u4 = *(const uint4*)(hw_s + wl * 1024 + ((unsigned)(c << 4) ^ wlx));
            const float* hrp = &hr_s[rr][ks * 32 + q * 8];
            float4 h0 = *(const float4*)(hrp);
            float4 h1 = *(const float4*)(hrp + 4);
            PKu pk;
            pk.us[0] = f32_to_bf16_rne(fmaxf(bf16_to_f32(hw.us[0]) + h0.x, 0.f));
            pk.us[1] = f32_to_bf16_rne(fmaxf(bf16_to_f32(hw.us[1]) + h0.y, 0.f));
            pk.us[2] = f32_to_bf16_rne(fmaxf(bf16_to_f32(hw.us[2]) + h0.z, 0.f));
            pk.us[3] = f32_to_bf16_rne(fmaxf(bf16_to_f32(hw.us[3]) + h0.w, 0.f));
            pk.us[4] = f32_to_bf16_rne(fmaxf(bf16_to_f32(hw.us[4]) + h1.x, 0.f));
            pk.us[5] = f32_to_bf16_rne(fmaxf(bf16_to_f32(hw.us[5]) + h1.y, 0.f));
            pk.us[6] = f32_to_bf16_rne(fmaxf(bf16_to_f32(hw.us[6]) + h1.z, 0.f));
            pk.us[7] = f32_to_bf16_rne(fmaxf(bf16_to_f32(hw.us[7]) + h1.w, 0.f));
#pragma unroll
            for (int ni = 0; ni < 2; ++ni)
                acc[ni] = __builtin_amdgcn_mfma_f32_16x16x32_bf16(
                    pk.s8, bfr[ni], acc[ni], 0, 0, 0);
        }
#pragma unroll
        for (int ni = 0; ni < 2; ++ni) {
            int c = ni * 16 + wl;
            if (c < CC) {
#pragma unroll
                for (int reg = 0; reg < 4; ++reg) {
                    int wg = wt * 16 + 4 * q + reg;
                    out_role[(size_t)((b * RR + rr) * WW + wg) * CC + c] =
                        acc[ni][reg] + b2[c];
                }
            }
        }
    }
}

extern "C" void kernel_launch(void* const* d_in, const int* in_sizes, int n_in,
                              void* d_out, int out_size, void* d_ws, size_t ws_size,
                              hipStream_t stream) {
    const float* hidden   = (const float*)d_in[0];
    const int*   word_ids = (const int*)d_in[1];
    const int*   relpos   = (const int*)d_in[2];
    const float* w_rel    = (const float*)d_in[3];
    const float* b_rel    = (const float*)d_in[4];
    const float* w1       = (const float*)d_in[5];
    const float* b1       = (const float*)d_in[6];
    const float* w2       = (const float*)d_in[7];
    const float* b2       = (const float*)d_in[8];

    float* out0 = (float*)d_out;                    // rel_logits [16*512]
    float* out1 = out0 + BB * SS;                   // role_logits [16*8*256*27]

    unsigned short* first_hidden = (unsigned short*)d_ws;
    unsigned short* rel_hidden   = (unsigned short*)((char*)d_ws + 6291456);
    unsigned short* w1t          = (unsigned short*)((char*)d_ws + 6488064);
    unsigned short* w2t          = (unsigned short*)((char*)d_ws + 8060928);
    unsigned short* h_word       = (unsigned short*)((char*)d_ws + 8093696);
    unsigned short* h_rel        = (unsigned short*)((char*)d_ws + 12288000);
    int*            flags        = (int*)((char*)d_ws + 12419072);
    int*            genl         = (int*)((char*)d_ws + 12451840);

    hipMemsetAsync(flags, 0, 40960, stream);
    k_all<<<NBLK, 512, 0, stream>>>(
        hidden, word_ids, relpos, (const float4*)w_rel, b_rel, w1, b1, w2, b2,
        out0, out1, first_hidden, rel_hidden, w1t, w2t, h_word, h_rel,
        flags, genl);
}

// Round 12
// 45.603 us; speedup vs baseline: 1.4665x; 1.4665x over previous
//
#include <hip/hip_runtime.h>
#include <hip/hip_bf16.h>

#define BB 16
#define SS 512
#define HH 768
#define RR 8
#define DD 512
#define CC 27
#define WW 256

typedef __attribute__((ext_vector_type(8))) short short8;
typedef __attribute__((ext_vector_type(4))) float f32x4;

union PKu { unsigned short us[8]; uint4 u4; short8 s8; };

__device__ __forceinline__ unsigned short f32_to_bf16_rne(float v) {
    unsigned int u = __float_as_uint(v);
    unsigned int r = u + 0x7fffu + ((u >> 16) & 1u);
    return (unsigned short)(r >> 16);
}
__device__ __forceinline__ float bf16_to_f32(unsigned short u) {
    return __uint_as_float(((unsigned int)u) << 16);
}
__device__ __forceinline__ void glds16(const void* g, void* l) {
    __builtin_amdgcn_global_load_lds(
        (const __attribute__((address_space(1))) unsigned int*)g,
        (__attribute__((address_space(3))) unsigned int*)l, 16, 0, 0);
}
__device__ __forceinline__ uint4 pack8(float4 f0, float4 f1) {
    PKu pk;
    pk.us[0] = f32_to_bf16_rne(f0.x);
    pk.us[1] = f32_to_bf16_rne(f0.y);
    pk.us[2] = f32_to_bf16_rne(f0.z);
    pk.us[3] = f32_to_bf16_rne(f0.w);
    pk.us[4] = f32_to_bf16_rne(f1.x);
    pk.us[5] = f32_to_bf16_rne(f1.y);
    pk.us[6] = f32_to_bf16_rne(f1.z);
    pk.us[7] = f32_to_bf16_rne(f1.w);
    return pk.u4;
}

// ---------------------------------------------------------------------------
// ws layout (bytes):
//   first_idx  : int[BB*WW]         @ 0         (16384)   -1 if word absent
//   rel_hidden : bf16[BB*RR][HH]    @ 16384     (196608)
//   w1t        : bf16[DD][2*HH]     @ 212992    (1572864)
//   w2t        : bf16[32][DD]       @ 1785856   (32768)
//   h_word     : bf16[BB*WW][DD]    @ 1818624   (4194304)  (+b1 folded)
//   h_rel      : bf16[BB*RR][DD]    @ 6012928   (131072)
// ---------------------------------------------------------------------------

// K1: 209 blocks. 0..191 w1t transpose; 192 w2t; 193.. per-batch first_idx + rel gather
__global__ __launch_bounds__(256) void k_prep(
    const float* __restrict__ w1, const float* __restrict__ w2,
    const int* __restrict__ word_ids, const int* __restrict__ relpos,
    const float* __restrict__ hidden, int* __restrict__ first_idx,
    unsigned short* __restrict__ rel_hidden,
    unsigned short* __restrict__ w1t, unsigned short* __restrict__ w2t) {
    int x = blockIdx.x, t = threadIdx.x;
    if (x < 192) {              // w1 [1536][512] f32 -> w1t [512][1536] bf16
        __shared__ unsigned short tile[64][72];
        int kt = x >> 3, nt = x & 7;
        int i = t >> 2, j4 = (t & 3) * 16;
        const float* src = w1 + (size_t)(kt * 64 + i) * DD + nt * 64 + j4;
#pragma unroll
        for (int v = 0; v < 4; ++v) {
            float4 f = *(const float4*)(src + v * 4);
            tile[i][j4 + v * 4 + 0] = f32_to_bf16_rne(f.x);
            tile[i][j4 + v * 4 + 1] = f32_to_bf16_rne(f.y);
            tile[i][j4 + v * 4 + 2] = f32_to_bf16_rne(f.z);
            tile[i][j4 + v * 4 + 3] = f32_to_bf16_rne(f.w);
        }
        __syncthreads();
        int jj = t >> 2, cb = (t & 3) * 16;
        union { unsigned short us[16]; uint4 u4[2]; } ov;
#pragma unroll
        for (int v = 0; v < 16; ++v) ov.us[v] = tile[cb + v][jj];
        unsigned short* dst = w1t + (size_t)(nt * 64 + jj) * (2 * HH) + kt * 64 + cb;
        *(uint4*)(dst) = ov.u4[0];
        *(uint4*)(dst + 8) = ov.u4[1];
    } else if (x == 192) {      // w2 [512][27] -> w2t [32][512] bf16
        for (int idx = t; idx < 32 * DD; idx += 256) {
            int n = idx >> 9, k = idx & (DD - 1);
            float v = (n < CC) ? w2[(size_t)k * CC + n] : 0.f;
            w2t[n * DD + k] = f32_to_bf16_rne(v);
        }
    } else {                    // per-batch: first_idx + rel gather
        int b = x - 193;
        first_idx[b * WW + t] = -1;
        __syncthreads();
        for (int s = t; s < SS; s += 256) {
            int wid = word_ids[b * SS + s];
            int prev = (s == 0) ? -1 : word_ids[b * SS + s - 1];
            if (wid != prev) first_idx[b * WW + wid] = s;
        }
        for (int idx = t; idx < RR * 96; idx += 256) {
            int rr = idx / 96, c = idx % 96;
            int pos = relpos[b * RR + rr];
            const float* srow = hidden + (size_t)(b * SS + pos) * HH + c * 8;
            float4 f0 = *(const float4*)(srow);
            float4 f1 = *(const float4*)(srow + 4);
            *(uint4*)(rel_hidden + (size_t)(b * RR + rr) * HH + c * 8) = pack8(f0, f1);
        }
    }
}

// K2: 776 blocks x 512 thr.
//   bid < 512 : rel_logits, 16 rows each (BW-bound, overlaps with gemm blocks)
//   bid 512..767: h_word gemm, A gathered from hidden via first_idx (reg-staged,
//                 T14 issue-early/write-late), B via glds. XCD-bijective mt map.
//   bid 768..775: h_rel gemm (A = rel_hidden via glds)
__global__ __launch_bounds__(512) void k_main(
    const float* __restrict__ hidden, const float4* __restrict__ wrel4,
    const float* __restrict__ b_rel, const int* __restrict__ first_idx,
    const unsigned short* __restrict__ rel_hidden,
    const unsigned short* __restrict__ w1t, const float* __restrict__ b1,
    float* __restrict__ out0, unsigned short* __restrict__ h_word,
    unsigned short* __restrict__ h_rel) {
    int bid = blockIdx.x, t = threadIdx.x;
    int wv = t >> 6, lane = t & 63;
    if (bid < 512) {            // ---- rel_logits: rows bid*16 .. +16
#pragma unroll
        for (int i = 0; i < 2; ++i) {
            int row = bid * 16 + wv * 2 + i;
            const float4* hid4 = (const float4*)hidden + (size_t)row * (HH / 4);
            float acc = 0.f;
#pragma unroll
            for (int c = 0; c < 3; ++c) {
                float4 v = hid4[c * 64 + lane];
                float4 w = wrel4[c * 64 + lane];
                acc += v.x * w.x + v.y * w.y + v.z * w.z + v.w * w.w;
            }
#pragma unroll
            for (int off = 32; off > 0; off >>= 1) acc += __shfl_xor(acc, off, 64);
            if (lane == 0) out0[row] = acc + b_rel[0];
        }
        return;
    }
    // ---- gemm: C = A @ w1t[:, kbase:+768]^T, 128x64 tile, BK=64, dbuf
    __shared__ __align__(16) unsigned char a_s[32768];  // 2 x [128 rows][128B]
    __shared__ __align__(16) unsigned char b_s[16384];  // 2 x [64 rows][128B]
    int j = bid - 512;
    int nt, mt;
    if (j < 256) {              // XCD-bijective: same-mt jobs share XCD j&7
        int xcd = j & 7, k = j >> 3;
        mt = xcd + 8 * (k & 3);
        nt = k >> 2;
    } else { mt = 32; nt = j - 256; }
    bool isw = (mt < 32);
    int kbase = isw ? 0 : HH;
    int m0 = isw ? mt * 128 : 0;
    int wr = wv >> 1, wc = wv & 1;
    int q = lane >> 4, r = lane & 15;

    // B staging (glds): 512 chunks, 1/thread
    const unsigned char* bP;
    unsigned lofb;
    {
        int row = t >> 3, ch = t & 7;
        int sc = ch ^ (row & 7);
        bP = (const unsigned char*)w1t + (size_t)(nt * 64 + row) * (2 * HH * 2)
             + (size_t)kbase * 2 + sc * 16;
        lofb = t * 16;
    }
    int arow[2], brow[2];
#pragma unroll
    for (int mi = 0; mi < 2; ++mi) arow[mi] = wr * 32 + mi * 16 + r;
#pragma unroll
    for (int ni = 0; ni < 2; ++ni) brow[ni] = wc * 32 + ni * 16 + r;

    f32x4 acc[2][2];
#pragma unroll
    for (int mi = 0; mi < 2; ++mi)
#pragma unroll
        for (int ni = 0; ni < 2; ++ni) acc[mi][ni] = (f32x4){0.f, 0.f, 0.f, 0.f};

    if (isw) {
        // A staging: gather f32 rows from hidden via first_idx, cvt, ds_write.
        // 1024 chunks / 512 thr = 2 per thread.
        const float* aSrc[2];
        unsigned aw_off[2];
        bool zro[2];
#pragma unroll
        for (int g = 0; g < 2; ++g) {
            int ci = g * 512 + t;
            int row = ci >> 3, ch = ci & 7;
            int grow = m0 + row;                 // = b*256 + w
            int src = first_idx[grow];
            zro[g] = (src < 0);
            aSrc[g] = hidden + (size_t)((grow >> 8) * SS + (src < 0 ? 0 : src)) * HH
                      + ch * 8;
            aw_off[g] = (unsigned)(row * 8 + (ch ^ (row & 7))) * 16;
        }
        uint4 zu4 = {0u, 0u, 0u, 0u};
        // prologue kt=0
        glds16(bP, b_s + lofb);
#pragma unroll
        for (int g = 0; g < 2; ++g) {
            uint4 av = zu4;
            if (!zro[g])
                av = pack8(*(const float4*)(aSrc[g]), *(const float4*)(aSrc[g] + 4));
            *(uint4*)(a_s + aw_off[g]) = av;
        }
        __syncthreads();
        for (int kt = 0; kt < 12; ++kt) {
            float4 pf[2][2];
            if (kt < 11) {      // issue next-tile loads early (hide under MFMA)
#pragma unroll
                for (int g = 0; g < 2; ++g)
                    if (!zro[g]) {
                        pf[g][0] = *(const float4*)(aSrc[g] + (kt + 1) * 64);
                        pf[g][1] = *(const float4*)(aSrc[g] + (kt + 1) * 64 + 4);
                    }
                glds16(bP + (kt + 1) * 128, b_s + ((kt + 1) & 1) * 8192 + lofb);
            }
            unsigned ba = (kt & 1) * 16384;
            unsigned bb = (kt & 1) * 8192;
#pragma unroll
            for (int ks = 0; ks < 2; ++ks) {
                int c = ks * 4 + q;
                short8 bfr[2];
#pragma unroll
                for (int ni = 0; ni < 2; ++ni)
                    bfr[ni] = *(const short8*)(b_s + bb + brow[ni] * 128 +
                                ((c ^ (brow[ni] & 7)) << 4));
#pragma unroll
                for (int mi = 0; mi < 2; ++mi) {
                    short8 af = *(const short8*)(a_s + ba + arow[mi] * 128 +
                                ((c ^ (arow[mi] & 7)) << 4));
                    acc[mi][0] = __builtin_amdgcn_mfma_f32_16x16x32_bf16(
                        af, bfr[0], acc[mi][0], 0, 0, 0);
                    acc[mi][1] = __builtin_amdgcn_mfma_f32_16x16x32_bf16(
                        af, bfr[1], acc[mi][1], 0, 0, 0);
                }
            }
            if (kt < 11) {      // write-late into other buffer
                unsigned na = ((kt + 1) & 1) * 16384;
#pragma unroll
                for (int g = 0; g < 2; ++g) {
                    uint4 av = zro[g] ? zu4 : pack8(pf[g][0], pf[g][1]);
                    *(uint4*)(a_s + na + aw_off[g]) = av;
                }
            }
            __syncthreads();
        }
    } else {
        // h_rel path: A = rel_hidden (contiguous bf16) via glds
        const unsigned char* aP[2];
        unsigned lofa[2];
#pragma unroll
        for (int g = 0; g < 2; ++g) {
            int ci = g * 512 + t;
            int row = ci >> 3, ch = ci & 7;
            int sc = ch ^ (row & 7);
            aP[g] = (const unsigned char*)rel_hidden + (size_t)row * (HH * 2) + sc * 16;
            lofa[g] = ci * 16;
        }
#pragma unroll
        for (int g = 0; g < 2; ++g) glds16(aP[g], a_s + lofa[g]);
        glds16(bP, b_s + lofb);
        __syncthreads();
        for (int kt = 0; kt < 12; ++kt) {
            if (kt < 11) {
                unsigned na = ((kt + 1) & 1) * 16384;
                unsigned nb = ((kt + 1) & 1) * 8192;
#pragma unroll
                for (int g = 0; g < 2; ++g)
                    glds16(aP[g] + (kt + 1) * 128, a_s + na + lofa[g]);
                glds16(bP + (kt + 1) * 128, b_s + nb + lofb);
            }
            unsigned ba = (kt & 1) * 16384;
            unsigned bb = (kt & 1) * 8192;
#pragma unroll
            for (int ks = 0; ks < 2; ++ks) {
                int c = ks * 4 + q;
                short8 bfr[2];
#pragma unroll
                for (int ni = 0; ni < 2; ++ni)
                    bfr[ni] = *(const short8*)(b_s + bb + brow[ni] * 128 +
                                ((c ^ (brow[ni] & 7)) << 4));
#pragma unroll
                for (int mi = 0; mi < 2; ++mi) {
                    short8 af = *(const short8*)(a_s + ba + arow[mi] * 128 +
                                ((c ^ (arow[mi] & 7)) << 4));
                    acc[mi][0] = __builtin_amdgcn_mfma_f32_16x16x32_bf16(
                        af, bfr[0], acc[mi][0], 0, 0, 0);
                    acc[mi][1] = __builtin_amdgcn_mfma_f32_16x16x32_bf16(
                        af, bfr[1], acc[mi][1], 0, 0, 0);
                }
            }
            __syncthreads();
        }
    }
    unsigned short* C = isw ? h_word : h_rel;
    float bias[2];
#pragma unroll
    for (int ni = 0; ni < 2; ++ni) {
        int n = nt * 64 + wc * 32 + ni * 16 + r;
        bias[ni] = isw ? b1[n] : 0.f;
    }
#pragma unroll
    for (int mi = 0; mi < 2; ++mi) {
        int m = m0 + wr * 32 + mi * 16 + q * 4;
#pragma unroll
        for (int ni = 0; ni < 2; ++ni) {
            int n = nt * 64 + wc * 32 + ni * 16 + r;
#pragma unroll
            for (int reg = 0; reg < 4; ++reg)
                C[(size_t)(m + reg) * DD + n] =
                    f32_to_bf16_rne(acc[mi][ni][reg] + bias[ni]);
        }
    }
}

// K3: role_logits = relu(h_word'[b,w,:]+h_rel[b,r,:]) @ w2 + b2 via MFMA.
__global__ __launch_bounds__(512) void k_role(
    const unsigned short* __restrict__ h_word, const unsigned short* __restrict__ h_rel,
    const unsigned short* __restrict__ w2t, const float* __restrict__ b2,
    float* __restrict__ out_role) {
    int wt = blockIdx.x;   // 0..15
    int b  = blockIdx.y;   // 0..15
    int t  = threadIdx.x;  // 512
    __shared__ __align__(16) unsigned char hw_s[16384];  // [16 w][512] bf16 swz
    __shared__ float hr_s[RR][DD];                       // 16 KB f32 linear
    __shared__ __align__(16) unsigned char w2_s[32768];  // [32 n][512] bf16 swz
    int wv = t >> 6, lane = t & 63;
#pragma unroll
    for (int i = 0; i < 2; ++i) {
        int row = wv * 2 + i;
        const unsigned short* src = h_word +
            (size_t)(b * WW + wt * 16 + row) * DD + ((lane ^ (row & 7)) * 8);
        glds16(src, hw_s + row * 1024 + lane * 16);
    }
#pragma unroll
    for (int i = 0; i < 4; ++i) {
        int row = wv * 4 + i;
        const unsigned short* src = w2t + row * DD + ((lane ^ (row & 7)) * 8);
        glds16(src, w2_s + row * 1024 + lane * 16);
    }
    {
        int rr = wv, c = lane;
        PKu hv;
        hv.u4 = *(const uint4*)(h_rel + (size_t)(b * RR + rr) * DD + c * 8);
        float4 o0, o1;
        o0.x = bf16_to_f32(hv.us[0]); o0.y = bf16_to_f32(hv.us[1]);
        o0.z = bf16_to_f32(hv.us[2]); o0.w = bf16_to_f32(hv.us[3]);
        o1.x = bf16_to_f32(hv.us[4]); o1.y = bf16_to_f32(hv.us[5]);
        o1.z = bf16_to_f32(hv.us[6]); o1.w = bf16_to_f32(hv.us[7]);
        *(float4*)&hr_s[rr][c * 8]     = o0;
        *(float4*)&hr_s[rr][c * 8 + 4] = o1;
    }
    __syncthreads();
    int q = lane >> 4, wl = lane & 15;
    int rr = wv;
    unsigned wlx = (wl & 7) << 4;
    f32x4 acc[2];
#pragma unroll
    for (int ni = 0; ni < 2; ++ni) acc[ni] = (f32x4){0.f, 0.f, 0.f, 0.f};

#pragma unroll 2
    for (int ks = 0; ks < DD / 32; ++ks) {
        int c = 4 * ks + q;
        short8 bfr[2];
#pragma unroll
        for (int ni = 0; ni < 2; ++ni) {
            int n = ni * 16 + wl;
            bfr[ni] = *(const short8*)(w2_s + n * 1024 + ((c ^ (n & 7)) << 4));
        }
        PKu hw;
        hw.u4 = *(const uint4*)(hw_s + wl * 1024 + ((unsigned)(c << 4) ^ wlx));
        const float* hrp = &hr_s[rr][ks * 32 + q * 8];
        float4 h0 = *(const float4*)(hrp);
        float4 h1 = *(const float4*)(hrp + 4);
        PKu pk;
        pk.us[0] = f32_to_bf16_rne(fmaxf(bf16_to_f32(hw.us[0]) + h0.x, 0.f));
        pk.us[1] = f32_to_bf16_rne(fmaxf(bf16_to_f32(hw.us[1]) + h0.y, 0.f));
        pk.us[2] = f32_to_bf16_rne(fmaxf(bf16_to_f32(hw.us[2]) + h0.z, 0.f));
        pk.us[3] = f32_to_bf16_rne(fmaxf(bf16_to_f32(hw.us[3]) + h0.w, 0.f));
        pk.us[4] = f32_to_bf16_rne(fmaxf(bf16_to_f32(hw.us[4]) + h1.x, 0.f));
        pk.us[5] = f32_to_bf16_rne(fmaxf(bf16_to_f32(hw.us[5]) + h1.y, 0.f));
        pk.us[6] = f32_to_bf16_rne(fmaxf(bf16_to_f32(hw.us[6]) + h1.z, 0.f));
        pk.us[7] = f32_to_bf16_rne(fmaxf(bf16_to_f32(hw.us[7]) + h1.w, 0.f));
#pragma unroll
        for (int ni = 0; ni < 2; ++ni)
            acc[ni] = __builtin_amdgcn_mfma_f32_16x16x32_bf16(
                pk.s8, bfr[ni], acc[ni], 0, 0, 0);
    }
#pragma unroll
    for (int ni = 0; ni < 2; ++ni) {
        int c = ni * 16 + wl;
        if (c < CC) {
#pragma unroll
            for (int reg = 0; reg < 4; ++reg) {
                int wg = wt * 16 + 4 * q + reg;
                out_role[(size_t)((b * RR + rr) * WW + wg) * CC + c] =
                    acc[ni][reg] + b2[c];
            }
        }
    }
}

extern "C" void kernel_launch(void* const* d_in, const int* in_sizes, int n_in,
                              void* d_out, int out_size, void* d_ws, size_t ws_size,
                              hipStream_t stream) {
    const float* hidden   = (const float*)d_in[0];
    const int*   word_ids = (const int*)d_in[1];
    const int*   relpos   = (const int*)d_in[2];
    const float* w_rel    = (const float*)d_in[3];
    const float* b_rel    = (const float*)d_in[4];
    const float* w1       = (const float*)d_in[5];
    const float* b1       = (const float*)d_in[6];
    const float* w2       = (const float*)d_in[7];
    const float* b2       = (const float*)d_in[8];

    float* out0 = (float*)d_out;                    // rel_logits [16*512]
    float* out1 = out0 + BB * SS;                   // role_logits [16*8*256*27]

    int*            first_idx  = (int*)d_ws;
    unsigned short* rel_hidden = (unsigned short*)((char*)d_ws + 16384);
    unsigned short* w1t        = (unsigned short*)((char*)d_ws + 212992);
    unsigned short* w2t        = (unsigned short*)((char*)d_ws + 1785856);
    unsigned short* h_word     = (unsigned short*)((char*)d_ws + 1818624);
    unsigned short* h_rel      = (unsigned short*)((char*)d_ws + 6012928);

    k_prep<<<209, 256, 0, stream>>>(w1, w2, word_ids, relpos, hidden,
                                    first_idx, rel_hidden, w1t, w2t);
    k_main<<<776, 512, 0, stream>>>(hidden, (const float4*)w_rel, b_rel,
                                    first_idx, rel_hidden, w1t, b1,
                                    out0, h_word, h_rel);
    k_role<<<dim3(WW / 16, BB), 512, 0, stream>>>(h_word, h_rel, w2t, b2, out1);
}

// Round 13
// 40.144 us; speedup vs baseline: 1.6660x; 1.1360x over previous
//
#include <hip/hip_runtime.h>
#include <hip/hip_bf16.h>

#define BB 16
#define SS 512
#define HH 768
#define RR 8
#define DD 512
#define CC 27
#define WW 256

typedef __attribute__((ext_vector_type(8))) short short8;
typedef __attribute__((ext_vector_type(4))) float f32x4;

union PKu { unsigned short us[8]; uint4 u4; short8 s8; };

__device__ __forceinline__ unsigned short f32_to_bf16_rne(float v) {
    unsigned int u = __float_as_uint(v);
    unsigned int r = u + 0x7fffu + ((u >> 16) & 1u);
    return (unsigned short)(r >> 16);
}
__device__ __forceinline__ float bf16_to_f32(unsigned short u) {
    return __uint_as_float(((unsigned int)u) << 16);
}

__device__ __forceinline__ void glds16(const void* g, void* l) {
    __builtin_amdgcn_global_load_lds(
        (const __attribute__((address_space(1))) unsigned int*)g,
        (__attribute__((address_space(3))) unsigned int*)l, 16, 0, 0);
}

// ---------------------------------------------------------------------------
// ws layout (bytes):
//   first_hidden : bf16[BB*WW][HH]   @ 0          (6291456)
//   rel_hidden   : bf16[BB*RR][HH]   @ 6291456    (196608)
//   w1t          : bf16[DD][2*HH]    @ 6488064    (1572864)
//   w2t          : bf16[32][DD]      @ 8060928    (32768)
//   h_word       : bf16[BB*WW][DD]   @ 8093696    (4194304)  (+b1 folded)
//   h_rel        : bf16[BB*RR][DD]   @ 12288000   (131072)
// ---------------------------------------------------------------------------

// K1: blocks 0..2047: rel_logits + first-occurrence scatter (1 wave per row)
//     blocks 2048..2256: w1t transpose / w2t / per-b zero + rel gather
__global__ __launch_bounds__(256) void k_front(
    const float* __restrict__ hidden, const int* __restrict__ word_ids,
    const int* __restrict__ relpos, const float4* __restrict__ wrel4,
    const float* __restrict__ b_rel, const float* __restrict__ w1,
    const float* __restrict__ w2, float* __restrict__ out0,
    unsigned short* __restrict__ first_hidden,
    unsigned short* __restrict__ rel_hidden,
    unsigned short* __restrict__ w1t, unsigned short* __restrict__ w2t) {
    int bid = blockIdx.x, t = threadIdx.x;
    if (bid < 2048) {
        int lane = t & 63;
        int row = bid * 4 + (t >> 6);            // b*512+s
        const float4* hid4 = (const float4*)hidden + (size_t)row * (HH / 4);
        float4 v[3];
        float acc = 0.f;
#pragma unroll
        for (int j = 0; j < 3; ++j) {
            v[j] = hid4[j * 64 + lane];
            float4 w = wrel4[j * 64 + lane];
            acc += v[j].x * w.x + v[j].y * w.y + v[j].z * w.z + v[j].w * w.w;
        }
#pragma unroll
        for (int off = 32; off > 0; off >>= 1) acc += __shfl_xor(acc, off, 64);
        if (lane == 0) out0[row] = acc + b_rel[0];
        int wid = word_ids[row];
        int s = row & (SS - 1);
        int prev = (s == 0) ? -1 : word_ids[row - 1];
        if (wid != prev) {                       // first occurrence (wave-uniform)
            int b = row >> 9;
            unsigned short* dst = first_hidden + (size_t)(b * WW + wid) * HH;
#pragma unroll
            for (int j = 0; j < 3; ++j) {
                union { unsigned short us[4]; uint2 u2; } pk;
                pk.us[0] = f32_to_bf16_rne(v[j].x);
                pk.us[1] = f32_to_bf16_rne(v[j].y);
                pk.us[2] = f32_to_bf16_rne(v[j].z);
                pk.us[3] = f32_to_bf16_rne(v[j].w);
                *(uint2*)(dst + j * 256 + lane * 4) = pk.u2;
            }
        }
        return;
    }
    int x = bid - 2048;
    if (x < 192) {              // w1 [1536][512] f32 -> w1t [512][1536] bf16
        __shared__ unsigned short tile[64][72];
        int kt = x >> 3, nt = x & 7;
        int i = t >> 2, j4 = (t & 3) * 16;
        const float* src = w1 + (size_t)(kt * 64 + i) * DD + nt * 64 + j4;
#pragma unroll
        for (int v = 0; v < 4; ++v) {
            float4 f = *(const float4*)(src + v * 4);
            tile[i][j4 + v * 4 + 0] = f32_to_bf16_rne(f.x);
            tile[i][j4 + v * 4 + 1] = f32_to_bf16_rne(f.y);
            tile[i][j4 + v * 4 + 2] = f32_to_bf16_rne(f.z);
            tile[i][j4 + v * 4 + 3] = f32_to_bf16_rne(f.w);
        }
        __syncthreads();
        int jj = t >> 2, cb = (t & 3) * 16;
        union { unsigned short us[16]; uint4 u4[2]; } ov;
#pragma unroll
        for (int v = 0; v < 16; ++v) ov.us[v] = tile[cb + v][jj];
        unsigned short* dst = w1t + (size_t)(nt * 64 + jj) * (2 * HH) + kt * 64 + cb;
        *(uint4*)(dst) = ov.u4[0];
        *(uint4*)(dst + 8) = ov.u4[1];
    } else if (x == 192) {      // w2 [512][27] -> w2t [32][512] bf16
        for (int idx = t; idx < 32 * DD; idx += 256) {
            int n = idx >> 9, k = idx & (DD - 1);
            float v = (n < CC) ? w2[(size_t)k * CC + n] : 0.f;
            w2t[n * DD + k] = f32_to_bf16_rne(v);
        }
    } else {                    // per-batch: zero absent rows + rel gather
        __shared__ int pres[WW];
        int b = x - 193;
        pres[t] = 0;
        __syncthreads();
        for (int s = t; s < SS; s += 256) pres[word_ids[b * SS + s]] = 1;
        __syncthreads();
        if (!pres[t]) {         // thread t owns word t
            uint4 z = {0u, 0u, 0u, 0u};
            unsigned short* dst = first_hidden + (size_t)(b * WW + t) * HH;
#pragma unroll 4
            for (int c = 0; c < 96; ++c) *(uint4*)(dst + c * 8) = z;
        }
        for (int idx = t; idx < 1024; idx += 256) {  // 8 rel rows x 96 chunks
            int rr = idx >> 7, c = idx & 127;
            if (c < 96) {
                int pos = relpos[b * RR + rr];
                const float* srow = hidden + (size_t)(b * SS + pos) * HH + c * 8;
                PKu pk;
#pragma unroll
                for (int e = 0; e < 8; ++e) pk.us[e] = f32_to_bf16_rne(srow[e]);
                *(uint4*)(rel_hidden + (size_t)(b * RR + rr) * HH + c * 8) = pk.u4;
            }
        }
    }
}

// K2: C = A @ w1t[:, kbase:kbase+768]^T, bf16 MFMA.
// 64x64 tile, BK=64, dbuf LDS (32KB -> >=2 blocks/CU for latency overlap),
// 4 waves 2x2, each 32x32 (2x2 frags). Grid 528:
//   bid<512: h_word, XCD-bijective (8 nt-blocks of one mt share XCD bid&7)
//   bid>=512: h_rel (M=128 -> 2 row-tiles x 8 nt)
__global__ __launch_bounds__(256) void k_gemm(
    const unsigned short* __restrict__ first_hidden,
    const unsigned short* __restrict__ rel_hidden,
    const unsigned short* __restrict__ w1t, const float* __restrict__ b1,
    unsigned short* __restrict__ h_word, unsigned short* __restrict__ h_rel) {
    __shared__ __align__(16) unsigned char a_s[16384];  // 2 x [64 rows][128B]
    __shared__ __align__(16) unsigned char b_s[16384];  // 2 x [64 rows][128B]
    int bid = blockIdx.x;
    int nt, m0;
    bool isw;
    if (bid < 512) {
        int xcd = bid & 7, k = bid >> 3;     // block bid -> XCD bid%8
        int mt = xcd + 8 * (k & 7);          // same-mt jobs share the XCD
        nt = k >> 3;
        isw = true;
        m0 = mt * 64;
    } else {
        int jj = bid - 512;
        isw = false;
        m0 = (jj >> 3) * 64;
        nt = jj & 7;
    }
    const unsigned short* A = isw ? first_hidden : rel_hidden;
    unsigned short* C = isw ? h_word : h_rel;
    int kbase = isw ? 0 : HH;
    int t = threadIdx.x;
    int wv = t >> 6, lane = t & 63;
    int wr = wv >> 1, wc = wv & 1;
    int q = lane >> 4, r = lane & 15;

    const unsigned char* aP[2];
    const unsigned char* bP[2];
    unsigned lofa[2], lofb[2];
#pragma unroll
    for (int g = 0; g < 2; ++g) {               // A/B: 64 rows x 8 chunks = 512 each
        int ci = g * 256 + t;
        int row = ci >> 3, ch = ci & 7;
        int sc = ch ^ (row & 7);                 // inverse-swizzled source chunk
        aP[g] = (const unsigned char*)A + (size_t)(m0 + row) * (HH * 2) + sc * 16;
        lofa[g] = ci * 16;
        bP[g] = (const unsigned char*)w1t + (size_t)(nt * 64 + row) * (2 * HH * 2)
                + (size_t)kbase * 2 + sc * 16;
        lofb[g] = ci * 16;
    }
    int arow[2], brow[2];
#pragma unroll
    for (int mi = 0; mi < 2; ++mi) arow[mi] = wr * 32 + mi * 16 + r;
#pragma unroll
    for (int ni = 0; ni < 2; ++ni) brow[ni] = wc * 32 + ni * 16 + r;

    f32x4 acc[2][2];
#pragma unroll
    for (int mi = 0; mi < 2; ++mi)
#pragma unroll
        for (int ni = 0; ni < 2; ++ni) acc[mi][ni] = (f32x4){0.f, 0.f, 0.f, 0.f};

    // prologue: stage kt=0 into buf 0
#pragma unroll
    for (int g = 0; g < 2; ++g) glds16(aP[g], a_s + lofa[g]);
#pragma unroll
    for (int g = 0; g < 2; ++g) glds16(bP[g], b_s + lofb[g]);
    __syncthreads();

    for (int kt = 0; kt < 12; ++kt) {
        if (kt < 11) {         // prefetch kt+1 into other buffer (hidden by MFMA)
            unsigned nb = ((kt + 1) & 1) * 8192;
#pragma unroll
            for (int g = 0; g < 2; ++g) glds16(aP[g] + (kt + 1) * 128, a_s + nb + lofa[g]);
#pragma unroll
            for (int g = 0; g < 2; ++g) glds16(bP[g] + (kt + 1) * 128, b_s + nb + lofb[g]);
        }
        unsigned bo = (kt & 1) * 8192;
#pragma unroll
        for (int ks = 0; ks < 2; ++ks) {
            int c = ks * 4 + q;
            short8 bfr[2];
#pragma unroll
            for (int ni = 0; ni < 2; ++ni)
                bfr[ni] = *(const short8*)(b_s + bo + brow[ni] * 128 +
                            ((c ^ (brow[ni] & 7)) << 4));
#pragma unroll
            for (int mi = 0; mi < 2; ++mi) {
                short8 af = *(const short8*)(a_s + bo + arow[mi] * 128 +
                            ((c ^ (arow[mi] & 7)) << 4));
                acc[mi][0] = __builtin_amdgcn_mfma_f32_16x16x32_bf16(
                    af, bfr[0], acc[mi][0], 0, 0, 0);
                acc[mi][1] = __builtin_amdgcn_mfma_f32_16x16x32_bf16(
                    af, bfr[1], acc[mi][1], 0, 0, 0);
            }
        }
        __syncthreads();
    }
    float bias[2];
#pragma unroll
    for (int ni = 0; ni < 2; ++ni) {
        int n = nt * 64 + wc * 32 + ni * 16 + r;
        bias[ni] = isw ? b1[n] : 0.f;
    }
#pragma unroll
    for (int mi = 0; mi < 2; ++mi) {
        int m = m0 + wr * 32 + mi * 16 + q * 4;
#pragma unroll
        for (int ni = 0; ni < 2; ++ni) {
            int n = nt * 64 + wc * 32 + ni * 16 + r;
#pragma unroll
            for (int reg = 0; reg < 4; ++reg)
                C[(size_t)(m + reg) * DD + n] =
                    f32_to_bf16_rne(acc[mi][ni][reg] + bias[ni]);
        }
    }
}

// K3: role_logits = relu(h_word'[b,w,:]+h_rel[b,r,:]) @ w2 + b2 via MFMA.
// 512 thr = 8 waves (one r each). LDS 64KB -> 2 blocks/CU.
__global__ __launch_bounds__(512) void k_role(
    const unsigned short* __restrict__ h_word, const unsigned short* __restrict__ h_rel,
    const unsigned short* __restrict__ w2t, const float* __restrict__ b2,
    float* __restrict__ out_role) {
    int wt = blockIdx.x;   // 0..15
    int b  = blockIdx.y;   // 0..15
    int t  = threadIdx.x;  // 512
    __shared__ __align__(16) unsigned char hw_s[16384];  // [16 w][512] bf16 swz
    __shared__ float hr_s[RR][DD];                       // 16 KB f32 linear
    __shared__ __align__(16) unsigned char w2_s[32768];  // [32 n][512] bf16 swz
    int wv = t >> 6, lane = t & 63;
#pragma unroll
    for (int i = 0; i < 2; ++i) {
        int row = wv * 2 + i;
        const unsigned short* src = h_word +
            (size_t)(b * WW + wt * 16 + row) * DD + ((lane ^ (row & 7)) * 8);
        glds16(src, hw_s + row * 1024 + lane * 16);
    }
#pragma unroll
    for (int i = 0; i < 4; ++i) {
        int row = wv * 4 + i;
        const unsigned short* src = w2t + row * DD + ((lane ^ (row & 7)) * 8);
        glds16(src, w2_s + row * 1024 + lane * 16);
    }
    {
        int rr = wv, c = lane;
        PKu hv;
        hv.u4 = *(const uint4*)(h_rel + (size_t)(b * RR + rr) * DD + c * 8);
        float4 o0, o1;
        o0.x = bf16_to_f32(hv.us[0]); o0.y = bf16_to_f32(hv.us[1]);
        o0.z = bf16_to_f32(hv.us[2]); o0.w = bf16_to_f32(hv.us[3]);
        o1.x = bf16_to_f32(hv.us[4]); o1.y = bf16_to_f32(hv.us[5]);
        o1.z = bf16_to_f32(hv.us[6]); o1.w = bf16_to_f32(hv.us[7]);
        *(float4*)&hr_s[rr][c * 8]     = o0;
        *(float4*)&hr_s[rr][c * 8 + 4] = o1;
    }
    __syncthreads();
    int q = lane >> 4, wl = lane & 15;
    int rr = wv;
    unsigned wlx = (wl & 7) << 4;
    f32x4 acc[2];
#pragma unroll
    for (int ni = 0; ni < 2; ++ni) acc[ni] = (f32x4){0.f, 0.f, 0.f, 0.f};

#pragma unroll 2
    for (int ks = 0; ks < DD / 32; ++ks) {
        int c = 4 * ks + q;
        short8 bfr[2];
#pragma unroll
        for (int ni = 0; ni < 2; ++ni) {
            int n = ni * 16 + wl;
            bfr[ni] = *(const short8*)(w2_s + n * 1024 + ((c ^ (n & 7)) << 4));
        }
        PKu hw;
        hw.u4 = *(const uint4*)(hw_s + wl * 1024 + ((unsigned)(c << 4) ^ wlx));
        const float* hrp = &hr_s[rr][ks * 32 + q * 8];
        float4 h0 = *(const float4*)(hrp);
        float4 h1 = *(const float4*)(hrp + 4);
        PKu pk;
        pk.us[0] = f32_to_bf16_rne(fmaxf(bf16_to_f32(hw.us[0]) + h0.x, 0.f));
        pk.us[1] = f32_to_bf16_rne(fmaxf(bf16_to_f32(hw.us[1]) + h0.y, 0.f));
        pk.us[2] = f32_to_bf16_rne(fmaxf(bf16_to_f32(hw.us[2]) + h0.z, 0.f));
        pk.us[3] = f32_to_bf16_rne(fmaxf(bf16_to_f32(hw.us[3]) + h0.w, 0.f));
        pk.us[4] = f32_to_bf16_rne(fmaxf(bf16_to_f32(hw.us[4]) + h1.x, 0.f));
        pk.us[5] = f32_to_bf16_rne(fmaxf(bf16_to_f32(hw.us[5]) + h1.y, 0.f));
        pk.us[6] = f32_to_bf16_rne(fmaxf(bf16_to_f32(hw.us[6]) + h1.z, 0.f));
        pk.us[7] = f32_to_bf16_rne(fmaxf(bf16_to_f32(hw.us[7]) + h1.w, 0.f));
#pragma unroll
        for (int ni = 0; ni < 2; ++ni)
            acc[ni] = __builtin_amdgcn_mfma_f32_16x16x32_bf16(
                pk.s8, bfr[ni], acc[ni], 0, 0, 0);
    }
#pragma unroll
    for (int ni = 0; ni < 2; ++ni) {
        int c = ni * 16 + wl;
        if (c < CC) {
#pragma unroll
            for (int reg = 0; reg < 4; ++reg) {
                int wg = wt * 16 + 4 * q + reg;
                out_role[(size_t)((b * RR + rr) * WW + wg) * CC + c] =
                    acc[ni][reg] + b2[c];
            }
        }
    }
}

extern "C" void kernel_launch(void* const* d_in, const int* in_sizes, int n_in,
                              void* d_out, int out_size, void* d_ws, size_t ws_size,
                              hipStream_t stream) {
    const float* hidden   = (const float*)d_in[0];
    const int*   word_ids = (const int*)d_in[1];
    const int*   relpos   = (const int*)d_in[2];
    const float* w_rel    = (const float*)d_in[3];
    const float* b_rel    = (const float*)d_in[4];
    const float* w1       = (const float*)d_in[5];
    const float* b1       = (const float*)d_in[6];
    const float* w2       = (const float*)d_in[7];
    const float* b2       = (const float*)d_in[8];

    float* out0 = (float*)d_out;                    // rel_logits [16*512]
    float* out1 = out0 + BB * SS;                   // role_logits [16*8*256*27]

    unsigned short* first_hidden = (unsigned short*)d_ws;
    unsigned short* rel_hidden   = (unsigned short*)((char*)d_ws + 6291456);
    unsigned short* w1t          = (unsigned short*)((char*)d_ws + 6488064);
    unsigned short* w2t          = (unsigned short*)((char*)d_ws + 8060928);
    unsigned short* h_word       = (unsigned short*)((char*)d_ws + 8093696);
    unsigned short* h_rel        = (unsigned short*)((char*)d_ws + 12288000);

    k_front<<<2048 + 209, 256, 0, stream>>>(
        hidden, word_ids, relpos, (const float4*)w_rel, b_rel, w1, w2,
        out0, first_hidden, rel_hidden, w1t, w2t);
    k_gemm<<<528, 256, 0, stream>>>(
        first_hidden, rel_hidden, w1t, b1, h_word, h_rel);
    k_role<<<dim3(WW / 16, BB), 512, 0, stream>>>(h_word, h_rel, w2t, b2, out1);
}

// Round 14
// 37.359 us; speedup vs baseline: 1.7901x; 1.0745x over previous
//
#include <hip/hip_runtime.h>
#include <hip/hip_bf16.h>

#define BB 16
#define SS 512
#define HH 768
#define RR 8
#define DD 512
#define CC 27
#define WW 256

typedef __attribute__((ext_vector_type(8))) short short8;
typedef __attribute__((ext_vector_type(4))) float f32x4;

union PKu { unsigned short us[8]; uint4 u4; short8 s8; };

__device__ __forceinline__ unsigned short f32_to_bf16_rne(float v) {
    unsigned int u = __float_as_uint(v);
    unsigned int r = u + 0x7fffu + ((u >> 16) & 1u);
    return (unsigned short)(r >> 16);
}
__device__ __forceinline__ float bf16_to_f32(unsigned short u) {
    return __uint_as_float(((unsigned int)u) << 16);
}

__device__ __forceinline__ void glds16(const void* g, void* l) {
    __builtin_amdgcn_global_load_lds(
        (const __attribute__((address_space(1))) unsigned int*)g,
        (__attribute__((address_space(3))) unsigned int*)l, 16, 0, 0);
}

// ---------------------------------------------------------------------------
// ws layout (bytes):
//   first_hidden : bf16[BB*WW][HH]   @ 0          (6291456)
//   rel_hidden   : bf16[BB*RR][HH]   @ 6291456    (196608)
//   w1t          : bf16[DD][2*HH]    @ 6488064    (1572864)
//   w2t          : bf16[32][DD]      @ 8060928    (32768)
//   h_word       : bf16[BB*WW][DD]   @ 8093696    (4194304)  (+b1 folded)
//   h_rel        : bf16[BB*RR][DD]   @ 12288000   (131072)
// ---------------------------------------------------------------------------

// K1 v2: 369 blocks x 512 thr.
//   bid<256   : rel_logits + first-occurrence scatter, 32 rows each (4-iter loop)
//   bid<352   : w1t transpose, 2 tiles/block (half-block per tile)
//   bid==352  : w2t
//   bid>=353  : per-batch zero absent rows + rel gather
__global__ __launch_bounds__(512) void k_front(
    const float* __restrict__ hidden, const int* __restrict__ word_ids,
    const int* __restrict__ relpos, const float4* __restrict__ wrel4,
    const float* __restrict__ b_rel, const float* __restrict__ w1,
    const float* __restrict__ w2, float* __restrict__ out0,
    unsigned short* __restrict__ first_hidden,
    unsigned short* __restrict__ rel_hidden,
    unsigned short* __restrict__ w1t, unsigned short* __restrict__ w2t) {
    int bid = blockIdx.x, t = threadIdx.x;
    int wv = t >> 6, lane = t & 63;
    if (bid < 256) {
#pragma unroll
        for (int it = 0; it < 4; ++it) {
            int row = bid * 32 + it * 8 + wv;    // b*512+s
            const float4* hid4 = (const float4*)hidden + (size_t)row * (HH / 4);
            float4 v[3];
            float acc = 0.f;
#pragma unroll
            for (int j = 0; j < 3; ++j) {
                v[j] = hid4[j * 64 + lane];
                float4 w = wrel4[j * 64 + lane];
                acc += v[j].x * w.x + v[j].y * w.y + v[j].z * w.z + v[j].w * w.w;
            }
#pragma unroll
            for (int off = 32; off > 0; off >>= 1) acc += __shfl_xor(acc, off, 64);
            if (lane == 0) out0[row] = acc + b_rel[0];
            int wid = word_ids[row];
            int s = row & (SS - 1);
            int prev = (s == 0) ? -1 : word_ids[row - 1];
            if (wid != prev) {                   // first occurrence (wave-uniform)
                int b = row >> 9;
                unsigned short* dst = first_hidden + (size_t)(b * WW + wid) * HH;
#pragma unroll
                for (int j = 0; j < 3; ++j) {
                    union { unsigned short us[4]; uint2 u2; } pk;
                    pk.us[0] = f32_to_bf16_rne(v[j].x);
                    pk.us[1] = f32_to_bf16_rne(v[j].y);
                    pk.us[2] = f32_to_bf16_rne(v[j].z);
                    pk.us[3] = f32_to_bf16_rne(v[j].w);
                    *(uint2*)(dst + j * 256 + lane * 4) = pk.u2;
                }
            }
        }
        return;
    }
    int x = bid - 256;
    if (x < 96) {               // w1 [1536][512] f32 -> w1t [512][1536] bf16
        __shared__ unsigned short tile[2][64][72];
        int half = t >> 8, tt = t & 255;
        int job = x * 2 + half;                  // 0..191
        int kt = job >> 3, nt = job & 7;
        int i = tt >> 2, j4 = (tt & 3) * 16;
        const float* src = w1 + (size_t)(kt * 64 + i) * DD + nt * 64 + j4;
#pragma unroll
        for (int v = 0; v < 4; ++v) {
            float4 f = *(const float4*)(src + v * 4);
            tile[half][i][j4 + v * 4 + 0] = f32_to_bf16_rne(f.x);
            tile[half][i][j4 + v * 4 + 1] = f32_to_bf16_rne(f.y);
            tile[half][i][j4 + v * 4 + 2] = f32_to_bf16_rne(f.z);
            tile[half][i][j4 + v * 4 + 3] = f32_to_bf16_rne(f.w);
        }
        __syncthreads();
        int jj = tt >> 2, cb = (tt & 3) * 16;
        union { unsigned short us[16]; uint4 u4[2]; } ov;
#pragma unroll
        for (int v = 0; v < 16; ++v) ov.us[v] = tile[half][cb + v][jj];
        unsigned short* dst = w1t + (size_t)(nt * 64 + jj) * (2 * HH) + kt * 64 + cb;
        *(uint4*)(dst) = ov.u4[0];
        *(uint4*)(dst + 8) = ov.u4[1];
    } else if (x == 96) {       // w2 [512][27] -> w2t [32][512] bf16
        for (int idx = t; idx < 32 * DD; idx += 512) {
            int n = idx >> 9, k = idx & (DD - 1);
            float v = (n < CC) ? w2[(size_t)k * CC + n] : 0.f;
            w2t[n * DD + k] = f32_to_bf16_rne(v);
        }
    } else {                    // per-batch: zero absent rows + rel gather
        __shared__ int pres[WW];
        int b = x - 97;
        if (t < WW) pres[t] = 0;
        __syncthreads();
        pres[word_ids[b * SS + t]] = 1;          // 512 threads cover all S
        __syncthreads();
        if (t < WW && !pres[t]) {                // thread t owns word t
            uint4 z = {0u, 0u, 0u, 0u};
            unsigned short* dst = first_hidden + (size_t)(b * WW + t) * HH;
#pragma unroll 4
            for (int c = 0; c < 96; ++c) *(uint4*)(dst + c * 8) = z;
        }
        for (int idx = t; idx < RR * 96; idx += 512) {
            int rr = idx / 96, c = idx % 96;
            int pos = relpos[b * RR + rr];
            const float* srow = hidden + (size_t)(b * SS + pos) * HH + c * 8;
            PKu pk;
#pragma unroll
            for (int e = 0; e < 8; ++e) pk.us[e] = f32_to_bf16_rne(srow[e]);
            *(uint4*)(rel_hidden + (size_t)(b * RR + rr) * HH + c * 8) = pk.u4;
        }
    }
}

// K2: C = A @ w1t[:, kbase:kbase+768]^T, bf16 MFMA.  (identical to R13)
// 64x64 tile, BK=64, dbuf LDS (32KB -> >=2 blocks/CU), 4 waves 2x2.
__global__ __launch_bounds__(256) void k_gemm(
    const unsigned short* __restrict__ first_hidden,
    const unsigned short* __restrict__ rel_hidden,
    const unsigned short* __restrict__ w1t, const float* __restrict__ b1,
    unsigned short* __restrict__ h_word, unsigned short* __restrict__ h_rel) {
    __shared__ __align__(16) unsigned char a_s[16384];  // 2 x [64 rows][128B]
    __shared__ __align__(16) unsigned char b_s[16384];  // 2 x [64 rows][128B]
    int bid = blockIdx.x;
    int nt, m0;
    bool isw;
    if (bid < 512) {
        int xcd = bid & 7, k = bid >> 3;     // block bid -> XCD bid%8
        int mt = xcd + 8 * (k & 7);          // same-mt jobs share the XCD
        nt = k >> 3;
        isw = true;
        m0 = mt * 64;
    } else {
        int jj = bid - 512;
        isw = false;
        m0 = (jj >> 3) * 64;
        nt = jj & 7;
    }
    const unsigned short* A = isw ? first_hidden : rel_hidden;
    unsigned short* C = isw ? h_word : h_rel;
    int kbase = isw ? 0 : HH;
    int t = threadIdx.x;
    int wv = t >> 6, lane = t & 63;
    int wr = wv >> 1, wc = wv & 1;
    int q = lane >> 4, r = lane & 15;

    const unsigned char* aP[2];
    const unsigned char* bP[2];
    unsigned lofa[2], lofb[2];
#pragma unroll
    for (int g = 0; g < 2; ++g) {               // A/B: 64 rows x 8 chunks = 512 each
        int ci = g * 256 + t;
        int row = ci >> 3, ch = ci & 7;
        int sc = ch ^ (row & 7);                 // inverse-swizzled source chunk
        aP[g] = (const unsigned char*)A + (size_t)(m0 + row) * (HH * 2) + sc * 16;
        lofa[g] = ci * 16;
        bP[g] = (const unsigned char*)w1t + (size_t)(nt * 64 + row) * (2 * HH * 2)
                + (size_t)kbase * 2 + sc * 16;
        lofb[g] = ci * 16;
    }
    int arow[2], brow[2];
#pragma unroll
    for (int mi = 0; mi < 2; ++mi) arow[mi] = wr * 32 + mi * 16 + r;
#pragma unroll
    for (int ni = 0; ni < 2; ++ni) brow[ni] = wc * 32 + ni * 16 + r;

    f32x4 acc[2][2];
#pragma unroll
    for (int mi = 0; mi < 2; ++mi)
#pragma unroll
        for (int ni = 0; ni < 2; ++ni) acc[mi][ni] = (f32x4){0.f, 0.f, 0.f, 0.f};

    // prologue: stage kt=0 into buf 0
#pragma unroll
    for (int g = 0; g < 2; ++g) glds16(aP[g], a_s + lofa[g]);
#pragma unroll
    for (int g = 0; g < 2; ++g) glds16(bP[g], b_s + lofb[g]);
    __syncthreads();

    for (int kt = 0; kt < 12; ++kt) {
        if (kt < 11) {         // prefetch kt+1 into other buffer (hidden by MFMA)
            unsigned nb = ((kt + 1) & 1) * 8192;
#pragma unroll
            for (int g = 0; g < 2; ++g) glds16(aP[g] + (kt + 1) * 128, a_s + nb + lofa[g]);
#pragma unroll
            for (int g = 0; g < 2; ++g) glds16(bP[g] + (kt + 1) * 128, b_s + nb + lofb[g]);
        }
        unsigned bo = (kt & 1) * 8192;
#pragma unroll
        for (int ks = 0; ks < 2; ++ks) {
            int c = ks * 4 + q;
            short8 bfr[2];
#pragma unroll
            for (int ni = 0; ni < 2; ++ni)
                bfr[ni] = *(const short8*)(b_s + bo + brow[ni] * 128 +
                            ((c ^ (brow[ni] & 7)) << 4));
#pragma unroll
            for (int mi = 0; mi < 2; ++mi) {
                short8 af = *(const short8*)(a_s + bo + arow[mi] * 128 +
                            ((c ^ (arow[mi] & 7)) << 4));
                acc[mi][0] = __builtin_amdgcn_mfma_f32_16x16x32_bf16(
                    af, bfr[0], acc[mi][0], 0, 0, 0);
                acc[mi][1] = __builtin_amdgcn_mfma_f32_16x16x32_bf16(
                    af, bfr[1], acc[mi][1], 0, 0, 0);
            }
        }
        __syncthreads();
    }
    float bias[2];
#pragma unroll
    for (int ni = 0; ni < 2; ++ni) {
        int n = nt * 64 + wc * 32 + ni * 16 + r;
        bias[ni] = isw ? b1[n] : 0.f;
    }
#pragma unroll
    for (int mi = 0; mi < 2; ++mi) {
        int m = m0 + wr * 32 + mi * 16 + q * 4;
#pragma unroll
        for (int ni = 0; ni < 2; ++ni) {
            int n = nt * 64 + wc * 32 + ni * 16 + r;
#pragma unroll
            for (int reg = 0; reg < 4; ++reg)
                C[(size_t)(m + reg) * DD + n] =
                    f32_to_bf16_rne(acc[mi][ni][reg] + bias[ni]);
        }
    }
}

// K3: role_logits = relu(h_word'[b,w,:]+h_rel[b,r,:]) @ w2 + b2 via MFMA.
// 512 thr = 8 waves (one r each). LDS 64KB -> 2 blocks/CU.  (identical to R13)
__global__ __launch_bounds__(512) void k_role(
    const unsigned short* __restrict__ h_word, const unsigned short* __restrict__ h_rel,
    const unsigned short* __restrict__ w2t, const float* __restrict__ b2,
    float* __restrict__ out_role) {
    int wt = blockIdx.x;   // 0..15
    int b  = blockIdx.y;   // 0..15
    int t  = threadIdx.x;  // 512
    __shared__ __align__(16) unsigned char hw_s[16384];  // [16 w][512] bf16 swz
    __shared__ float hr_s[RR][DD];                       // 16 KB f32 linear
    __shared__ __align__(16) unsigned char w2_s[32768];  // [32 n][512] bf16 swz
    int wv = t >> 6, lane = t & 63;
#pragma unroll
    for (int i = 0; i < 2; ++i) {
        int row = wv * 2 + i;
        const unsigned short* src = h_word +
            (size_t)(b * WW + wt * 16 + row) * DD + ((lane ^ (row & 7)) * 8);
        glds16(src, hw_s + row * 1024 + lane * 16);
    }
#pragma unroll
    for (int i = 0; i < 4; ++i) {
        int row = wv * 4 + i;
        const unsigned short* src = w2t + row * DD + ((lane ^ (row & 7)) * 8);
        glds16(src, w2_s + row * 1024 + lane * 16);
    }
    {
        int rr = wv, c = lane;
        PKu hv;
        hv.u4 = *(const uint4*)(h_rel + (size_t)(b * RR + rr) * DD + c * 8);
        float4 o0, o1;
        o0.x = bf16_to_f32(hv.us[0]); o0.y = bf16_to_f32(hv.us[1]);
        o0.z = bf16_to_f32(hv.us[2]); o0.w = bf16_to_f32(hv.us[3]);
        o1.x = bf16_to_f32(hv.us[4]); o1.y = bf16_to_f32(hv.us[5]);
        o1.z = bf16_to_f32(hv.us[6]); o1.w = bf16_to_f32(hv.us[7]);
        *(float4*)&hr_s[rr][c * 8]     = o0;
        *(float4*)&hr_s[rr][c * 8 + 4] = o1;
    }
    __syncthreads();
    int q = lane >> 4, wl = lane & 15;
    int rr = wv;
    unsigned wlx = (wl & 7) << 4;
    f32x4 acc[2];
#pragma unroll
    for (int ni = 0; ni < 2; ++ni) acc[ni] = (f32x4){0.f, 0.f, 0.f, 0.f};

#pragma unroll 2
    for (int ks = 0; ks < DD / 32; ++ks) {
        int c = 4 * ks + q;
        short8 bfr[2];
#pragma unroll
        for (int ni = 0; ni < 2; ++ni) {
            int n = ni * 16 + wl;
            bfr[ni] = *(const short8*)(w2_s + n * 1024 + ((c ^ (n & 7)) << 4));
        }
        PKu hw;
        hw.u4 = *(const uint4*)(hw_s + wl * 1024 + ((unsigned)(c << 4) ^ wlx));
        const float* hrp = &hr_s[rr][ks * 32 + q * 8];
        float4 h0 = *(const float4*)(hrp);
        float4 h1 = *(const float4*)(hrp + 4);
        PKu pk;
        pk.us[0] = f32_to_bf16_rne(fmaxf(bf16_to_f32(hw.us[0]) + h0.x, 0.f));
        pk.us[1] = f32_to_bf16_rne(fmaxf(bf16_to_f32(hw.us[1]) + h0.y, 0.f));
        pk.us[2] = f32_to_bf16_rne(fmaxf(bf16_to_f32(hw.us[2]) + h0.z, 0.f));
        pk.us[3] = f32_to_bf16_rne(fmaxf(bf16_to_f32(hw.us[3]) + h0.w, 0.f));
        pk.us[4] = f32_to_bf16_rne(fmaxf(bf16_to_f32(hw.us[4]) + h1.x, 0.f));
        pk.us[5] = f32_to_bf16_rne(fmaxf(bf16_to_f32(hw.us[5]) + h1.y, 0.f));
        pk.us[6] = f32_to_bf16_rne(fmaxf(bf16_to_f32(hw.us[6]) + h1.z, 0.f));
        pk.us[7] = f32_to_bf16_rne(fmaxf(bf16_to_f32(hw.us[7]) + h1.w, 0.f));
#pragma unroll
        for (int ni = 0; ni < 2; ++ni)
            acc[ni] = __builtin_amdgcn_mfma_f32_16x16x32_bf16(
                pk.s8, bfr[ni], acc[ni], 0, 0, 0);
    }
#pragma unroll
    for (int ni = 0; ni < 2; ++ni) {
        int c = ni * 16 + wl;
        if (c < CC) {
#pragma unroll
            for (int reg = 0; reg < 4; ++reg) {
                int wg = wt * 16 + 4 * q + reg;
                out_role[(size_t)((b * RR + rr) * WW + wg) * CC + c] =
                    acc[ni][reg] + b2[c];
            }
        }
    }
}

extern "C" void kernel_launch(void* const* d_in, const int* in_sizes, int n_in,
                              void* d_out, int out_size, void* d_ws, size_t ws_size,
                              hipStream_t stream) {
    const float* hidden   = (const float*)d_in[0];
    const int*   word_ids = (const int*)d_in[1];
    const int*   relpos   = (const int*)d_in[2];
    const float* w_rel    = (const float*)d_in[3];
    const float* b_rel    = (const float*)d_in[4];
    const float* w1       = (const float*)d_in[5];
    const float* b1       = (const float*)d_in[6];
    const float* w2       = (const float*)d_in[7];
    const float* b2       = (const float*)d_in[8];

    float* out0 = (float*)d_out;                    // rel_logits [16*512]
    float* out1 = out0 + BB * SS;                   // role_logits [16*8*256*27]

    unsigned short* first_hidden = (unsigned short*)d_ws;
    unsigned short* rel_hidden   = (unsigned short*)((char*)d_ws + 6291456);
    unsigned short* w1t          = (unsigned short*)((char*)d_ws + 6488064);
    unsigned short* w2t          = (unsigned short*)((char*)d_ws + 8060928);
    unsigned short* h_word       = (unsigned short*)((char*)d_ws + 8093696);
    unsigned short* h_rel        = (unsigned short*)((char*)d_ws + 12288000);

    k_front<<<369, 512, 0, stream>>>(
        hidden, word_ids, relpos, (const float4*)w_rel, b_rel, w1, w2,
        out0, first_hidden, rel_hidden, w1t, w2t);
    k_gemm<<<528, 256, 0, stream>>>(
        first_hidden, rel_hidden, w1t, b1, h_word, h_rel);
    k_role<<<dim3(WW / 16, BB), 512, 0, stream>>>(h_word, h_rel, w2t, b2, out1);
}